// Round 5
// baseline (274.555 us; speedup 1.0000x reference)
//
#include <hip/hip_runtime.h>

#define HD 32
#define NHEADS 12
#define HH 56
#define WW 56
#define NN (HH * WW)
#define BB 8
#define CC (HD * NHEADS)
#define SCALE 0.17677669529663689f

// Wave-local design: lane = pair*8 + cg. cg (lane&7) owns 4 channels; pr
// (lane>>3) selects one of 8 position-pairs per wave. Partial QK logits are
// combined across the 8 channel groups with __shfl_xor(1|2|4) -- register-only,
// no LDS, no __syncthreads anywhere. Per-thread live state ~34 regs by design
// (r0-r4 lesson: occupancy x bytes-in-flight is the binding constraint; this is
// the first variant with BOTH wide loads and high occupancy).
// P=2 + dilation=2: the 3 dx taps are three disjoint 8B-aligned float2 loads.
// Boundaries are branchless: clamped addresses + 0/1 masks on logits (QK) and
// on post-softmax weights (PV), reproducing unfold zero-padding exactly.
// 1568 pairs per (b,head) = 49 blocks x 32 pairs exactly -> no tail predicate.
__global__ __launch_bounds__(256) void dilate_attn_kernel(
    const float* __restrict__ q,
    const float* __restrict__ k,
    const float* __restrict__ v,
    float* __restrict__ out)
{
    const int lane = threadIdx.x & 63;
    const int wid  = threadIdx.x >> 6;          // wave in block: 0..3
    const int cg   = lane & 7;                  // channel group: 4 channels
    const int pr   = lane >> 3;                 // pair within wave: 0..7
    const int pair = (blockIdx.x * 4 + wid) * 8 + pr;   // 0..1567 exact
    const int n0   = 2 * pair;
    const int bh   = blockIdx.y;
    const int b    = bh / NHEADS;
    const int head = bh - b * NHEADS;

    const int y  = n0 / WW;
    const int x0 = n0 - y * WW;                 // even, 0..54
    const float mlo = (x0 == 0)      ? 0.f : 1.f;
    const float mhi = (x0 == WW - 2) ? 0.f : 1.f;
    const int offlo = (x0 == 0)      ? 0 : -2;  // clamped: masked anyway
    const int offhi = (x0 == WW - 2) ? 0 :  2;

    const int base0 = (b * CC + head * HD + cg * 4) * NN;

    // ---- q fragment: 4 channels x 2 positions ----
    float qv[4][2];
#pragma unroll
    for (int d = 0; d < 4; ++d) {
        const float2 t = *reinterpret_cast<const float2*>(q + base0 + d * NN + n0);
        qv[d][0] = t.x; qv[d][1] = t.y;
    }

    // ---- QK: partial logits, branchless masking ----
    float lg[9][2];
    float rm[3];
#pragma unroll
    for (int r = 0; r < 3; ++r) {
        const int ny = y + (r - 1) * 2;
        rm[r] = ((unsigned)ny < HH) ? 1.f : 0.f;
        const int nyc = ny < 0 ? 0 : (ny > HH - 1 ? HH - 1 : ny);
        const int rowbase = base0 + nyc * WW + x0;
        float s0x = 0.f, s0y = 0.f, s1x = 0.f, s1y = 0.f, s2x = 0.f, s2y = 0.f;
#pragma unroll
        for (int d = 0; d < 4; ++d) {
            const float* kb = k + rowbase + d * NN;
            const float2 w0 = *reinterpret_cast<const float2*>(kb + offlo);
            const float2 w1 = *reinterpret_cast<const float2*>(kb);
            const float2 w2 = *reinterpret_cast<const float2*>(kb + offhi);
            s0x = fmaf(qv[d][0], w0.x, s0x); s0y = fmaf(qv[d][1], w0.y, s0y);
            s1x = fmaf(qv[d][0], w1.x, s1x); s1y = fmaf(qv[d][1], w1.y, s1y);
            s2x = fmaf(qv[d][0], w2.x, s2x); s2y = fmaf(qv[d][1], w2.y, s2y);
        }
        const float m0 = rm[r] * mlo, m2 = rm[r] * mhi;
        lg[r * 3 + 0][0] = s0x * m0;    lg[r * 3 + 0][1] = s0y * m0;
        lg[r * 3 + 1][0] = s1x * rm[r]; lg[r * 3 + 1][1] = s1y * rm[r];
        lg[r * 3 + 2][0] = s2x * m2;    lg[r * 3 + 2][1] = s2y * m2;
    }

    // ---- combine the 8 channel groups: register-only butterfly ----
#pragma unroll
    for (int t = 0; t < 9; ++t) {
#pragma unroll
        for (int j = 0; j < 2; ++j) {
            float s = lg[t][j];
            s += __shfl_xor(s, 1);
            s += __shfl_xor(s, 2);
            s += __shfl_xor(s, 4);
            lg[t][j] = s;
        }
    }

    // ---- softmax over 9 taps (duplicated across the 8 cg lanes; cheap) ----
#pragma unroll
    for (int j = 0; j < 2; ++j) {
        float m = lg[0][j] * SCALE;
#pragma unroll
        for (int t = 0; t < 9; ++t) { lg[t][j] *= SCALE; m = fmaxf(m, lg[t][j]); }
        float s = 0.f;
#pragma unroll
        for (int t = 0; t < 9; ++t) { const float e = __expf(lg[t][j] - m); lg[t][j] = e; s += e; }
        const float inv = 1.f / s;
#pragma unroll
        for (int t = 0; t < 9; ++t) lg[t][j] *= inv;
    }
    // re-mask: invalid taps have nonzero softmax weight but v==0 in the ref
#pragma unroll
    for (int r = 0; r < 3; ++r) {
        lg[r * 3 + 0][0] *= rm[r] * mlo; lg[r * 3 + 0][1] *= rm[r] * mlo;
        lg[r * 3 + 1][0] *= rm[r];       lg[r * 3 + 1][1] *= rm[r];
        lg[r * 3 + 2][0] *= rm[r] * mhi; lg[r * 3 + 2][1] *= rm[r] * mhi;
    }

    // ---- PV: same disjoint float2 taps from v ----
    float acc[4][2];
#pragma unroll
    for (int d = 0; d < 4; ++d) { acc[d][0] = 0.f; acc[d][1] = 0.f; }
#pragma unroll
    for (int r = 0; r < 3; ++r) {
        const int ny = y + (r - 1) * 2;
        const int nyc = ny < 0 ? 0 : (ny > HH - 1 ? HH - 1 : ny);
        const int rowbase = base0 + nyc * WW + x0;
        const float w0x = lg[r * 3 + 0][0], w0y = lg[r * 3 + 0][1];
        const float w1x = lg[r * 3 + 1][0], w1y = lg[r * 3 + 1][1];
        const float w2x = lg[r * 3 + 2][0], w2y = lg[r * 3 + 2][1];
#pragma unroll
        for (int d = 0; d < 4; ++d) {
            const float* vb = v + rowbase + d * NN;
            const float2 u0 = *reinterpret_cast<const float2*>(vb + offlo);
            const float2 u1 = *reinterpret_cast<const float2*>(vb);
            const float2 u2 = *reinterpret_cast<const float2*>(vb + offhi);
            acc[d][0] = fmaf(w0x, u0.x, acc[d][0]); acc[d][1] = fmaf(w0y, u0.y, acc[d][1]);
            acc[d][0] = fmaf(w1x, u1.x, acc[d][0]); acc[d][1] = fmaf(w1y, u1.y, acc[d][1]);
            acc[d][0] = fmaf(w2x, u2.x, acc[d][0]); acc[d][1] = fmaf(w2y, u2.y, acc[d][1]);
        }
    }

    // ---- store: out[b, y, x0+j, head*32 + cg*4 + 0..3] ----
#pragma unroll
    for (int j = 0; j < 2; ++j) {
        float* ob = out + ((b * HH + y) * WW + (x0 + j)) * CC + head * HD + cg * 4;
        *reinterpret_cast<float4*>(ob) =
            make_float4(acc[0][j], acc[1][j], acc[2][j], acc[3][j]);
    }
}

extern "C" void kernel_launch(void* const* d_in, const int* in_sizes, int n_in,
                              void* d_out, int out_size, void* d_ws, size_t ws_size,
                              hipStream_t stream) {
    const float* q = (const float*)d_in[0];
    const float* k = (const float*)d_in[1];
    const float* v = (const float*)d_in[2];
    float* out = (float*)d_out;

    dim3 block(256);
    dim3 grid(49, BB * NHEADS);   // 49 blocks x 32 pairs = 1568 pairs = NN/2 exact
    dilate_attn_kernel<<<grid, block, 0, stream>>>(q, k, v, out);
}

// Round 7
// 165.646 us; speedup vs baseline: 1.6575x; 1.6575x over previous
//
#include <hip/hip_runtime.h>

#define HD 32
#define NHEADS 12
#define HH 56
#define WW 56
#define NN (HH * WW)
#define BB 8
#define CC (HD * NHEADS)
#define SCALE 0.17677669529663689f

// Round-6 structure (resubmitted unchanged after infra failure):
//  * block (64,4): threadIdx.y = channel quarter (8 ch); wave = 64 lanes of the
//    SAME quarter covering 112 positions = exactly 2 full rows (tx 0..55
//    active, 56..63 idle -> 12.5% lane waste, accepted).
//  * Only the CENTER tap (dx=0) is loaded from memory. The dx=-2/+2 windows
//    are lane tx-1 / tx+1's center tap -> __shfl_up/__shfl_down(1).
//    Row-crossing neighbors occur only at x0==0 / x0==54 lanes, which are
//    exactly the zero-masked taps (unfold zero-padding) -> masks make the
//    shuffled garbage harmless. 3x fewer vmem instructions than r4.
//  * FULL prefetch: q(8)+k(24)+v(24) float2 = 112 VGPRs of data issued as 56
//    independent branchless loads before any use -> ONE exposed latency
//    round-trip per thread (r0-r5: all variants were latency-bound with ~6
//    serialized round-trips; v-loads no longer wait for softmax).
//  * Combine across quarters: LDS exchange (r4 layout, measured 0 conflicts).
__global__ __launch_bounds__(256) void dilate_attn_kernel(
    const float* __restrict__ q,
    const float* __restrict__ k,
    const float* __restrict__ v,
    float* __restrict__ out)
{
    const int tx = threadIdx.x;            // 0..63 (pair within 2-row stripe)
    const int qc = threadIdx.y;            // 0..3 channel quarter
    const int bh = blockIdx.y;
    const int b = bh / NHEADS;
    const int head = bh - b * NHEADS;

    const int n0r = blockIdx.x * 112 + 2 * tx;
    const int n0 = (n0r <= NN - 2) ? n0r : NN - 2;   // clamp idle lanes
    const bool active = (tx < 56);

    const int y  = n0 / WW;
    const int x0 = n0 - y * WW;            // even; block base is row-aligned
    const float mlo = (x0 == 0)      ? 0.f : 1.f;
    const float mhi = (x0 == WW - 2) ? 0.f : 1.f;

    const int base0 = (b * CC + head * HD + qc * 8) * NN;

    __shared__ float2 part[4][64][9];      // 18432 B logit exchange

    // ---- prefetch: 56 independent float2 loads, no branches ----
    float2 qv[8];
#pragma unroll
    for (int d = 0; d < 8; ++d)
        qv[d] = *reinterpret_cast<const float2*>(q + base0 + d * NN + n0);

    float rm[3]; int rb[3];
#pragma unroll
    for (int r = 0; r < 3; ++r) {
        const int ny = y + (r - 1) * 2;
        rm[r] = ((unsigned)ny < HH) ? 1.f : 0.f;
        const int nyc = ny < 0 ? 0 : (ny > HH - 1 ? HH - 1 : ny);
        rb[r] = base0 + nyc * WW + x0;
    }

    float2 km[3][8];
#pragma unroll
    for (int r = 0; r < 3; ++r)
#pragma unroll
        for (int d = 0; d < 8; ++d)
            km[r][d] = *reinterpret_cast<const float2*>(k + rb[r] + d * NN);

    float2 vm[3][8];
#pragma unroll
    for (int r = 0; r < 3; ++r)
#pragma unroll
        for (int d = 0; d < 8; ++d)
            vm[r][d] = *reinterpret_cast<const float2*>(v + rb[r] + d * NN);

    // ---- QK: center tap local, side taps via lane shuffles ----
    float lg[9][2];
#pragma unroll
    for (int r = 0; r < 3; ++r) {
        float s0x = 0.f, s0y = 0.f, s1x = 0.f, s1y = 0.f, s2x = 0.f, s2y = 0.f;
#pragma unroll
        for (int d = 0; d < 8; ++d) {
            const float2 w1 = km[r][d];
            const float w0x = __shfl_up(w1.x, 1);
            const float w0y = __shfl_up(w1.y, 1);
            const float w2x = __shfl_down(w1.x, 1);
            const float w2y = __shfl_down(w1.y, 1);
            s0x = fmaf(qv[d].x, w0x, s0x);  s0y = fmaf(qv[d].y, w0y, s0y);
            s1x = fmaf(qv[d].x, w1.x, s1x); s1y = fmaf(qv[d].y, w1.y, s1y);
            s2x = fmaf(qv[d].x, w2x, s2x);  s2y = fmaf(qv[d].y, w2y, s2y);
        }
        const float m0 = rm[r] * mlo, m2 = rm[r] * mhi;
        lg[r * 3 + 0][0] = s0x * m0;    lg[r * 3 + 0][1] = s0y * m0;
        lg[r * 3 + 1][0] = s1x * rm[r]; lg[r * 3 + 1][1] = s1y * rm[r];
        lg[r * 3 + 2][0] = s2x * m2;    lg[r * 3 + 2][1] = s2y * m2;
    }

    // ---- combine quarters via LDS (one barrier) ----
#pragma unroll
    for (int t = 0; t < 9; ++t) part[qc][tx][t] = make_float2(lg[t][0], lg[t][1]);
    __syncthreads();
#pragma unroll
    for (int o = 1; o < 4; ++o) {
        const int oq = (qc + o) & 3;
#pragma unroll
        for (int t = 0; t < 9; ++t) {
            const float2 p = part[oq][tx][t];
            lg[t][0] += p.x; lg[t][1] += p.y;
        }
    }

    // ---- softmax over 9 taps (dup per quarter; cheap) ----
#pragma unroll
    for (int j = 0; j < 2; ++j) {
        float m = lg[0][j] * SCALE;
#pragma unroll
        for (int t = 0; t < 9; ++t) { lg[t][j] *= SCALE; m = fmaxf(m, lg[t][j]); }
        float s = 0.f;
#pragma unroll
        for (int t = 0; t < 9; ++t) { const float e = __expf(lg[t][j] - m); lg[t][j] = e; s += e; }
        const float inv = 1.f / s;
#pragma unroll
        for (int t = 0; t < 9; ++t) lg[t][j] *= inv;
    }
    // re-mask: invalid taps have nonzero softmax weight but v==0 in the ref
#pragma unroll
    for (int r = 0; r < 3; ++r) {
        const float m0 = rm[r] * mlo, m2 = rm[r] * mhi;
        lg[r * 3 + 0][0] *= m0;    lg[r * 3 + 0][1] *= m0;
        lg[r * 3 + 1][0] *= rm[r]; lg[r * 3 + 1][1] *= rm[r];
        lg[r * 3 + 2][0] *= m2;    lg[r * 3 + 2][1] *= m2;
    }

    // ---- PV: center tap local, side taps via lane shuffles ----
    float acc[8][2];
#pragma unroll
    for (int d = 0; d < 8; ++d) { acc[d][0] = 0.f; acc[d][1] = 0.f; }
#pragma unroll
    for (int r = 0; r < 3; ++r) {
        const float g0x = lg[r * 3 + 0][0], g0y = lg[r * 3 + 0][1];
        const float g1x = lg[r * 3 + 1][0], g1y = lg[r * 3 + 1][1];
        const float g2x = lg[r * 3 + 2][0], g2y = lg[r * 3 + 2][1];
#pragma unroll
        for (int d = 0; d < 8; ++d) {
            const float2 u1 = vm[r][d];
            const float u0x = __shfl_up(u1.x, 1);
            const float u0y = __shfl_up(u1.y, 1);
            const float u2x = __shfl_down(u1.x, 1);
            const float u2y = __shfl_down(u1.y, 1);
            acc[d][0] = fmaf(g0x, u0x, acc[d][0]);  acc[d][1] = fmaf(g0y, u0y, acc[d][1]);
            acc[d][0] = fmaf(g1x, u1.x, acc[d][0]); acc[d][1] = fmaf(g1y, u1.y, acc[d][1]);
            acc[d][0] = fmaf(g2x, u2x, acc[d][0]);  acc[d][1] = fmaf(g2y, u2y, acc[d][1]);
        }
    }

    // ---- store: out[b, y, x0+j, head*32 + qc*8 + 0..7] ----
    if (active) {
#pragma unroll
        for (int j = 0; j < 2; ++j) {
            float* ob = out + ((b * HH + y) * WW + (x0 + j)) * CC + head * HD + qc * 8;
            *reinterpret_cast<float4*>(ob)     = make_float4(acc[0][j], acc[1][j], acc[2][j], acc[3][j]);
            *reinterpret_cast<float4*>(ob + 4) = make_float4(acc[4][j], acc[5][j], acc[6][j], acc[7][j]);
        }
    }
}

extern "C" void kernel_launch(void* const* d_in, const int* in_sizes, int n_in,
                              void* d_out, int out_size, void* d_ws, size_t ws_size,
                              hipStream_t stream) {
    const float* q = (const float*)d_in[0];
    const float* k = (const float*)d_in[1];
    const float* v = (const float*)d_in[2];
    float* out = (float*)d_out;

    dim3 block(64, 4);
    dim3 grid(NN / 112, BB * NHEADS);   // 28 x 96; 28*112 = 3136 = NN exact
    dilate_attn_kernel<<<grid, block, 0, stream>>>(q, k, v, out);
}